// Round 4
// baseline (1060.760 us; speedup 1.0000x reference)
//
#include <hip/hip_runtime.h>

#define NNODES 100000
#define NEDGES 3200000
#define NFEAT  512
#define NHID   16
#define NCLS   64
#define NB     391      // ceil(100000/256) buckets of 256 nodes (bucket = dst>>8)
#define CAP    10240    // per-bucket edge capacity (mean 8192, sd ~90 -> +22 sigma)
#define EPB    8192     // edges per block in partition pass
#define GTPB   8        // gemm tiles (16 rows) per block in fused path
#define NGB    782      // ceil(6250 tiles / 8)

typedef short bf16x8 __attribute__((ext_vector_type(8)));
typedef float f32x4  __attribute__((ext_vector_type(4)));

__device__ __forceinline__ short f2bf(float f) {
    unsigned u = __float_as_uint(f);
    return (short)((u + 0x7FFFu + ((u >> 16) & 1u)) >> 16);
}
__device__ __forceinline__ float bf2f(unsigned short u) {
    return __uint_as_float((unsigned)u << 16);
}

struct PartShared {
    unsigned hist[NB];
    unsigned scn[512];
    unsigned cursor[NB];
    unsigned delta[NB];
    unsigned staged[EPB];
    unsigned short pbkt[EPB];
};
struct GemmShared {
    short w1t[16][520];
};
union FusedShared { PartShared p; GemmShared g; };

// ---- K1: blocks [0,NB) partition edges into buckets; blocks [NB,NB+NGB) do x@W1.
// The two jobs are independent -> one dispatch overlaps sort latency with gemm HBM reads.
__global__ __launch_bounds__(512) void k_fused1(const int* __restrict__ src,
                                                const int* __restrict__ dst,
                                                unsigned* __restrict__ gcnt,
                                                unsigned* __restrict__ part,
                                                const float* __restrict__ x,
                                                const float* __restrict__ w1,
                                                unsigned short* __restrict__ hs1) {
    __shared__ FusedShared sh;
    int t = threadIdx.x;
    if (blockIdx.x < NB) {
        // ---------- partition path (identical logic to proven k_part) ----------
        int base = blockIdx.x * EPB;
        int nblk = min(EPB, NEDGES - base);
        for (int i = t; i < NB; i += 512) sh.p.hist[i] = 0;
        __syncthreads();
        unsigned pk[16]; unsigned short bk[16];
#pragma unroll
        for (int j = 0; j < 16; ++j) {
            int o = t + j * 512;
            if (o < nblk) {
                int s = src[base + o], d = dst[base + o];
                pk[j] = (unsigned)s | ((unsigned)(d & 255) << 17);
                bk[j] = (unsigned short)(d >> 8);
                atomicAdd(&sh.p.hist[bk[j]], 1u);
            } else bk[j] = 0xFFFFu;
        }
        __syncthreads();
        sh.p.scn[t] = (t < NB) ? sh.p.hist[t] : 0u;
        __syncthreads();
#pragma unroll
        for (int off = 1; off < 512; off <<= 1) {
            unsigned a = (t >= off) ? sh.p.scn[t - off] : 0u;
            __syncthreads();
            sh.p.scn[t] += a;
            __syncthreads();
        }
        for (int i = t; i < NB; i += 512) {
            unsigned h = sh.p.hist[i];
            unsigned ex = sh.p.scn[i] - h;
            sh.p.cursor[i] = ex;
            unsigned gb = h ? atomicAdd(&gcnt[i], h) : 0u;
            sh.p.delta[i] = (unsigned)i * CAP + gb - ex;
        }
        __syncthreads();
#pragma unroll
        for (int j = 0; j < 16; ++j) {
            if (bk[j] != 0xFFFFu) {
                unsigned p = atomicAdd(&sh.p.cursor[bk[j]], 1u);
                sh.p.staged[p] = pk[j];
                sh.p.pbkt[p] = bk[j];
            }
        }
        __syncthreads();
        for (int i = t; i < nblk; i += 512) {
            unsigned b = sh.p.pbkt[i];
            unsigned d = sh.p.delta[b] + (unsigned)i;
            if (d < (b + 1u) * CAP) part[d] = sh.p.staged[i];
        }
    } else {
        // ---------- gemm path: hs1 = bf16(x @ W1), UNSCALED (dinv applied at scatter) ----------
        for (int idx = t; idx < NFEAT * NHID; idx += 512) {
            int k = idx >> 4, n = idx & 15;
            sh.g.w1t[n][k] = f2bf(w1[idx]);
        }
        __syncthreads();
        int wave = t >> 6, lane = t & 63;
        int tile = (int)(blockIdx.x - NB) * GTPB + wave;
        if (tile >= NNODES / 16) return;
        int m = lane & 15, q = lane >> 4;
        const float* xrow = x + (size_t)(tile * 16 + m) * NFEAT + q * 8;
        const short* wrow = &sh.g.w1t[m][q * 8];
        f32x4 acc = {0.f, 0.f, 0.f, 0.f};
#pragma unroll
        for (int kb = 0; kb < NFEAT / 32; ++kb) {
            float4 a0 = *(const float4*)(xrow + kb * 32);
            float4 a1 = *(const float4*)(xrow + kb * 32 + 4);
            bf16x8 a;
            a[0] = f2bf(a0.x); a[1] = f2bf(a0.y); a[2] = f2bf(a0.z); a[3] = f2bf(a0.w);
            a[4] = f2bf(a1.x); a[5] = f2bf(a1.y); a[6] = f2bf(a1.z); a[7] = f2bf(a1.w);
            bf16x8 b = *(const bf16x8*)(wrow + kb * 32);
            acc = __builtin_amdgcn_mfma_f32_16x16x32_bf16(a, b, acc, 0, 0, 0);
        }
        unsigned short* outp = hs1 + (size_t)(tile * 16) * NHID;
#pragma unroll
        for (int r = 0; r < 4; ++r)
            outp[(q * 4 + r) * NHID + m] = (unsigned short)f2bf(acc[r]);
    }
}

// ---- K2: per-bucket degree histogram -> dinv (replaces the whole fine-sort pass)
__global__ __launch_bounds__(512) void k_dinv(const unsigned* __restrict__ gcnt,
                                              const unsigned* __restrict__ part,
                                              float* __restrict__ dinv) {
    __shared__ unsigned hist[256];
    int t = threadIdx.x, b = blockIdx.x;
    unsigned cb = min(gcnt[b], (unsigned)CAP);
    const unsigned* seg = part + (size_t)b * CAP;
    if (t < 256) hist[t] = 0;
    __syncthreads();
    for (unsigned i = t; i < cb; i += 512)
        atomicAdd(&hist[(seg[i] >> 17) & 255u], 1u);
    __syncthreads();
    if (t < 256) {
        int gn = b * 256 + t;
        if (gn < NNODES) dinv[gn] = rsqrtf((float)hist[t] + 1.f);  // +1 = self-loop
    }
}

// ---- K3: layer-1 scatter-add into LDS acc + self + bias + relu -> hs2 (pre-scaled)
// fire-and-forget ds_add_f32: no gather latency chain, MLP-limited.
__global__ __launch_bounds__(512) void k_sc1(const unsigned* __restrict__ gcnt,
                                             const unsigned* __restrict__ part,
                                             const float* __restrict__ dinv,
                                             const unsigned short* __restrict__ hs1,
                                             const float* __restrict__ b1,
                                             unsigned short* __restrict__ hs2) {
    __shared__ float acc[256 * 16];     // 16 KB
    __shared__ unsigned pld[2048];      // 8 KB payload stage
    int t = threadIdx.x, b = blockIdx.x;
    for (int i = t; i < 4096; i += 512) acc[i] = 0.f;
    unsigned cb = min(gcnt[b], (unsigned)CAP);
    const unsigned* seg = part + (size_t)b * CAP;
    int f = t & 15, eslot = t >> 4;     // 16 lanes per edge, 32 edge-slots
    for (unsigned chunk = 0; chunk < cb; chunk += 2048) {
        int n = (int)min(2048u, cb - chunk);
        for (int i = t; i < n; i += 512) pld[i] = seg[chunk + i];
        __syncthreads();
        for (int base = 0; base < n; base += 256) {   // 256 edges in flight per pass
            float m[8]; int nl[8]; bool ok[8];
#pragma unroll
            for (int u = 0; u < 8; ++u) {
                int e = base + u * 32 + eslot;
                ok[u] = e < n;
                unsigned p = pld[ok[u] ? e : 0];
                int s = (int)(p & 0x1FFFFu);
                nl[u] = (int)((p >> 17) & 255u);
                float ds = dinv[s];                       // broadcast across 16 lanes
                m[u] = bf2f(hs1[(size_t)s * NHID + f]) * ds;
            }
#pragma unroll
            for (int u = 0; u < 8; ++u)
                if (ok[u]) atomicAdd(&acc[nl[u] * 16 + f], m[u]);
        }
        __syncthreads();
    }
    // self-loop + bias + relu + pre-scale, store bf16
    for (int i = t; i < 4096; i += 512) {
        int nd = i >> 4, ff = i & 15;
        int gn = b * 256 + nd;
        if (gn < NNODES) {
            float di = dinv[gn];
            float v = (acc[i] + bf2f(hs1[(size_t)gn * NHID + ff]) * di) * di + b1[ff];
            v = v > 0.f ? v : 0.f;
            hs2[(size_t)gn * NHID + ff] = (unsigned short)f2bf(v * di);
        }
    }
}

// ---- K4: layer-2 scatter-add + self + W2 matvec + b2 + log_softmax
__global__ __launch_bounds__(512) void k_sc2(const unsigned* __restrict__ gcnt,
                                             const unsigned* __restrict__ part,
                                             const float* __restrict__ dinv,
                                             const unsigned short* __restrict__ hs2,
                                             const float* __restrict__ w2,
                                             const float* __restrict__ b2,
                                             float* __restrict__ out) {
    __shared__ float acc[256 * 16];
    __shared__ unsigned pld[2048];
    int t = threadIdx.x, b = blockIdx.x;
    int lane = t & 63, wv = t >> 6;
    // each lane's W2 column + bias in registers (no LDS, no extra barrier)
    float w2c[NHID];
#pragma unroll
    for (int k = 0; k < NHID; ++k) w2c[k] = w2[k * NCLS + lane];
    float bb = b2[lane];
    for (int i = t; i < 4096; i += 512) acc[i] = 0.f;
    unsigned cb = min(gcnt[b], (unsigned)CAP);
    const unsigned* seg = part + (size_t)b * CAP;
    int f = t & 15, eslot = t >> 4;
    for (unsigned chunk = 0; chunk < cb; chunk += 2048) {
        int n = (int)min(2048u, cb - chunk);
        for (int i = t; i < n; i += 512) pld[i] = seg[chunk + i];
        __syncthreads();
        for (int base = 0; base < n; base += 256) {
            float m[8]; int nl[8]; bool ok[8];
#pragma unroll
            for (int u = 0; u < 8; ++u) {
                int e = base + u * 32 + eslot;
                ok[u] = e < n;
                unsigned p = pld[ok[u] ? e : 0];
                int s = (int)(p & 0x1FFFFu);
                nl[u] = (int)((p >> 17) & 255u);
                m[u] = bf2f(hs2[(size_t)s * NHID + f]);   // hs2 already pre-scaled
            }
#pragma unroll
            for (int u = 0; u < 8; ++u)
                if (ok[u]) atomicAdd(&acc[nl[u] * 16 + f], m[u]);
        }
        __syncthreads();
    }
    // finalize v = (acc + self) * dinv  (in-place in LDS)
    for (int i = t; i < 4096; i += 512) {
        int nd = i >> 4, ff = i & 15;
        int gn = b * 256 + nd;
        if (gn < NNODES)
            acc[i] = (acc[i] + bf2f(hs2[(size_t)gn * NHID + ff])) * dinv[gn];
    }
    __syncthreads();
    // per-node class phase: wave = node, lane = class
    for (int nd = wv; nd < 256; nd += 8) {
        int gn = b * 256 + nd;
        if (gn >= NNODES) continue;
        float logit = bb;
#pragma unroll
        for (int k = 0; k < NHID; ++k)
            logit += acc[nd * 16 + k] * w2c[k];           // LDS broadcast read
        float mx = logit;
#pragma unroll
        for (int off = 32; off > 0; off >>= 1) mx = fmaxf(mx, __shfl_xor(mx, off));
        float ex = __expf(logit - mx);
        float s = ex;
#pragma unroll
        for (int off = 32; off > 0; off >>= 1) s += __shfl_xor(s, off);
        out[(size_t)gn * NCLS + lane] = logit - mx - logf(s);
    }
}

extern "C" void kernel_launch(void* const* d_in, const int* in_sizes, int n_in,
                              void* d_out, int out_size, void* d_ws, size_t ws_size,
                              hipStream_t stream) {
    const float* x  = (const float*)d_in[0];   // f32 [100000,512]
    const int*   ei = (const int*)d_in[1];     // int32 [2,3200000]
    const float* w1 = (const float*)d_in[2];   // f32 [512,16]
    const float* b1 = (const float*)d_in[3];   // f32 [16]
    const float* w2 = (const float*)d_in[4];   // f32 [16,64]
    const float* b2 = (const float*)d_in[5];   // f32 [64]
    const int* src = ei;
    const int* dst = ei + NEDGES;

    char* ws = (char*)d_ws;
    unsigned* gcnt = (unsigned*)(ws + 0);          //     2,048 B
    float*    dinv = (float*)   (ws + 2048);       //   400,000 B
    unsigned short* hs1 = (unsigned short*)(ws + 402048);   // 3,200,000 B (bf16)
    unsigned short* hs2 = (unsigned short*)(ws + 3602048);  // 3,200,000 B (bf16)
    unsigned* part = (unsigned*)(ws + 6802048);    // 16,015,360 B (total ~22.8 MB)

    hipMemsetAsync(gcnt, 0, 2048, stream);
    k_fused1<<<NB + NGB, 512, 0, stream>>>(src, dst, gcnt, part, x, w1, hs1);
    k_dinv  <<<NB, 512, 0, stream>>>(gcnt, part, dinv);
    k_sc1   <<<NB, 512, 0, stream>>>(gcnt, part, dinv, hs1, b1, hs2);
    k_sc2   <<<NB, 512, 0, stream>>>(gcnt, part, dinv, hs2, w2, b2, (float*)d_out);
}

// Round 5
// 470.874 us; speedup vs baseline: 2.2527x; 2.2527x over previous
//
#include <hip/hip_runtime.h>

#define NNODES 100000
#define NEDGES 3200000
#define NFEAT  512
#define NHID   16
#define NCLS   64
#define NB     391      // ceil(100000/256) buckets of 256 nodes (bucket = dst>>8)
#define CAP    10240    // per-bucket edge capacity (mean 8192, sd ~90 -> +22 sigma)
#define EPB    4096     // edges per partition block (782 blocks)
#define NPB    782      // ceil(NEDGES/EPB)
#define GTPB   8        // gemm tiles (16 rows) per block (8 waves x 1 tile)
#define NGB    782      // ceil(6250 tiles / 8)

typedef short bf16x8 __attribute__((ext_vector_type(8)));
typedef float f32x4  __attribute__((ext_vector_type(4)));

__device__ __forceinline__ short f2bf(float f) {
    unsigned u = __float_as_uint(f);
    return (short)((u + 0x7FFFu + ((u >> 16) & 1u)) >> 16);
}
__device__ __forceinline__ float bf2f(unsigned short u) {
    return __uint_as_float((unsigned)u << 16);
}

struct PartShared {
    unsigned hist[NB];
    unsigned scn[512];
    unsigned cursor[NB];
    unsigned delta[NB];
    unsigned staged[EPB];
    unsigned short pbkt[EPB];
};                                  // ~31.3 KB
struct GemmShared { short w1t[16][520]; };   // 16.6 KB
union FusedShared { PartShared p; GemmShared g; };

// ---- K1: blocks [0,NPB) partition edges into 391 buckets; blocks [NPB,NPB+NGB) do x@W1.
// Independent jobs in one dispatch: gemm's HBM streaming overlaps partition latency.
__global__ __launch_bounds__(512) void k_fused1(const int* __restrict__ src,
                                                const int* __restrict__ dst,
                                                unsigned* __restrict__ gcnt,
                                                unsigned* __restrict__ part,
                                                const float* __restrict__ x,
                                                const float* __restrict__ w1,
                                                unsigned short* __restrict__ hs1) {
    __shared__ FusedShared sh;
    int t = threadIdx.x;
    if (blockIdx.x < NPB) {
        // ---------- partition path (R3's proven k_part logic, EPB=4096) ----------
        int base = blockIdx.x * EPB;
        int nblk = min(EPB, NEDGES - base);
        for (int i = t; i < NB; i += 512) sh.p.hist[i] = 0;
        __syncthreads();
        unsigned pk[8]; unsigned short bk[8];
#pragma unroll
        for (int j = 0; j < 8; ++j) {
            int o = t + j * 512;
            if (o < nblk) {
                int s = src[base + o], d = dst[base + o];
                pk[j] = (unsigned)s | ((unsigned)(d & 255) << 17);
                bk[j] = (unsigned short)(d >> 8);
                atomicAdd(&sh.p.hist[bk[j]], 1u);
            } else bk[j] = 0xFFFFu;
        }
        __syncthreads();
        sh.p.scn[t] = (t < NB) ? sh.p.hist[t] : 0u;
        __syncthreads();
#pragma unroll
        for (int off = 1; off < 512; off <<= 1) {
            unsigned a = (t >= off) ? sh.p.scn[t - off] : 0u;
            __syncthreads();
            sh.p.scn[t] += a;
            __syncthreads();
        }
        for (int i = t; i < NB; i += 512) {
            unsigned h = sh.p.hist[i];
            unsigned ex = sh.p.scn[i] - h;
            sh.p.cursor[i] = ex;
            unsigned gb = h ? atomicAdd(&gcnt[i], h) : 0u;
            sh.p.delta[i] = (unsigned)i * CAP + gb - ex;
        }
        __syncthreads();
#pragma unroll
        for (int j = 0; j < 8; ++j) {
            if (bk[j] != 0xFFFFu) {
                unsigned p = atomicAdd(&sh.p.cursor[bk[j]], 1u);
                sh.p.staged[p] = pk[j];
                sh.p.pbkt[p] = bk[j];
            }
        }
        __syncthreads();
        for (int i = t; i < nblk; i += 512) {
            unsigned b = sh.p.pbkt[i];
            unsigned d = sh.p.delta[b] + (unsigned)i;
            if (d < (b + 1u) * CAP) part[d] = sh.p.staged[i];
        }
    } else {
        // ---------- gemm path: hs1 = bf16(x @ W1), UNSCALED (dinv applied at gather) ----------
        for (int idx = t; idx < NFEAT * NHID; idx += 512) {
            int k = idx >> 4, n = idx & 15;
            sh.g.w1t[n][k] = f2bf(w1[idx]);
        }
        __syncthreads();
        int wave = t >> 6, lane = t & 63;
        int tile = (int)(blockIdx.x - NPB) * GTPB + wave;
        if (tile >= NNODES / 16) return;
        int m = lane & 15, q = lane >> 4;
        const float* xrow = x + (size_t)(tile * 16 + m) * NFEAT + q * 8;
        const short* wrow = &sh.g.w1t[m][q * 8];
        f32x4 acc = {0.f, 0.f, 0.f, 0.f};
#pragma unroll
        for (int kb = 0; kb < NFEAT / 32; ++kb) {
            float4 a0 = *(const float4*)(xrow + kb * 32);
            float4 a1 = *(const float4*)(xrow + kb * 32 + 4);
            bf16x8 a;
            a[0] = f2bf(a0.x); a[1] = f2bf(a0.y); a[2] = f2bf(a0.z); a[3] = f2bf(a0.w);
            a[4] = f2bf(a1.x); a[5] = f2bf(a1.y); a[6] = f2bf(a1.z); a[7] = f2bf(a1.w);
            bf16x8 b = *(const bf16x8*)(wrow + kb * 32);
            acc = __builtin_amdgcn_mfma_f32_16x16x32_bf16(a, b, acc, 0, 0, 0);
        }
        unsigned short* outp = hs1 + (size_t)(tile * 16) * NHID;
#pragma unroll
        for (int r = 0; r < 4; ++r)
            outp[(q * 4 + r) * NHID + m] = (unsigned short)f2bf(acc[r]);
    }
}

// ---- K2: per-bucket fine CSR (degree, offsets, dinv) + in-place sorted rewrite (R3 verbatim)
__global__ __launch_bounds__(512) void k_csr(const unsigned* __restrict__ gcnt,
                                             unsigned* __restrict__ part,
                                             unsigned* __restrict__ offs,
                                             unsigned* __restrict__ cnt,
                                             float* __restrict__ dinv) {
    __shared__ unsigned hist[256], nst[256], cursor[256];
    __shared__ unsigned staged[CAP];
    int t = threadIdx.x, b = blockIdx.x;
    unsigned cb = min(gcnt[b], (unsigned)CAP);
    unsigned* seg = part + (size_t)b * CAP;
    if (t < 256) hist[t] = 0;
    __syncthreads();
    for (unsigned i = t; i < cb; i += 512)
        atomicAdd(&hist[(seg[i] >> 17) & 255u], 1u);
    __syncthreads();
    if (t < 256) nst[t] = hist[t];
    __syncthreads();
#pragma unroll
    for (int off = 1; off < 256; off <<= 1) {
        unsigned a = (t >= off && t < 256) ? nst[t - off] : 0u;
        __syncthreads();
        if (t < 256) nst[t] += a;
        __syncthreads();
    }
    if (t < 256) {
        unsigned ex = nst[t] - hist[t];
        cursor[t] = ex;
        int node = b * 256 + t;
        if (node < NNODES) {
            offs[node] = (unsigned)b * CAP + ex;
            cnt[node] = hist[t];
            dinv[node] = rsqrtf((float)hist[t] + 1.f);  // +1 = self-loop
        }
    }
    __syncthreads();
    for (unsigned i = t; i < cb; i += 512) {
        unsigned p = seg[i];
        unsigned r = atomicAdd(&cursor[(p >> 17) & 255u], 1u);
        staged[r] = p & 0x1FFFFu;                       // src only
    }
    __syncthreads();
    for (unsigned i = t; i < cb; i += 512)
        seg[i] = staged[i];                             // coalesced in-place rewrite
}

// ---- K3: layer-1 aggregate; hs1 unscaled -> per-edge dinv[src]; batch-16 (64 edges in flight)
__global__ __launch_bounds__(256) void k_agg1(const unsigned* __restrict__ offs,
                                              const unsigned* __restrict__ cnt,
                                              const unsigned* __restrict__ eb,
                                              const unsigned short* __restrict__ hs1,
                                              const float* __restrict__ dinv,
                                              const float* __restrict__ b1,
                                              unsigned short* __restrict__ hs2) {
    int tid = threadIdx.x;
    int node = blockIdx.x * 4 + (tid >> 6);
    int lane = tid & 63, f = lane & 15, slot = lane >> 4;
    unsigned start = offs[node];
    int deg = (int)cnt[node];
    float di = dinv[node];
    float acc = 0.f;
    int rounds = (deg + 63) >> 6;                       // 1 round for P(deg<=64) ~ 1-1e-7
    int cl = deg - 1;
    for (int r = 0; r < rounds; ++r) {
        int jb = r * 64 + slot * 16;
        unsigned e[16];
#pragma unroll
        for (int u = 0; u < 16; ++u) e[u] = eb[start + min(jb + u, cl)];
        float d[16], a[16];
#pragma unroll
        for (int u = 0; u < 16; ++u) d[u] = dinv[e[u]];
#pragma unroll
        for (int u = 0; u < 16; ++u) a[u] = bf2f(hs1[(size_t)e[u] * NHID + f]);
#pragma unroll
        for (int u = 0; u < 16; ++u) acc += (jb + u < deg) ? a[u] * d[u] : 0.f;
    }
    acc += __shfl_xor(acc, 16);
    acc += __shfl_xor(acc, 32);
    float v = (acc + bf2f(hs1[(size_t)node * NHID + f]) * di) * di + b1[f];
    v = v > 0.f ? v : 0.f;
    if (slot == 0) hs2[(size_t)node * NHID + f] = (unsigned short)f2bf(v * di);
}

// ---- K4: layer-2 aggregate + self + W2 matvec + b2 + log_softmax; batch-16; hs2 pre-scaled
__global__ __launch_bounds__(256) void k_out2(const unsigned* __restrict__ offs,
                                              const unsigned* __restrict__ cnt,
                                              const unsigned* __restrict__ eb,
                                              const unsigned short* __restrict__ hs2,
                                              const float* __restrict__ dinv,
                                              const float* __restrict__ w2,
                                              const float* __restrict__ b2,
                                              float* __restrict__ out) {
    int tid = threadIdx.x;
    int node = blockIdx.x * 4 + (tid >> 6);
    int lane = tid & 63, f = lane & 15, slot = lane >> 4;
    unsigned start = offs[node];
    int deg = (int)cnt[node];
    float di = dinv[node];
    float w2c[NHID];
#pragma unroll
    for (int k = 0; k < NHID; ++k) w2c[k] = w2[k * NCLS + lane];
    float bb = b2[lane];
    float acc = 0.f;
    int rounds = (deg + 63) >> 6;
    int cl = deg - 1;
    for (int r = 0; r < rounds; ++r) {
        int jb = r * 64 + slot * 16;
        unsigned e[16];
#pragma unroll
        for (int u = 0; u < 16; ++u) e[u] = eb[start + min(jb + u, cl)];
        float a[16];
#pragma unroll
        for (int u = 0; u < 16; ++u) a[u] = bf2f(hs2[(size_t)e[u] * NHID + f]);
#pragma unroll
        for (int u = 0; u < 16; ++u) acc += (jb + u < deg) ? a[u] : 0.f;
    }
    acc += __shfl_xor(acc, 16);
    acc += __shfl_xor(acc, 32);
    float v = (acc + bf2f(hs2[(size_t)node * NHID + f])) * di;
    float logit = bb;
#pragma unroll
    for (int k = 0; k < NHID; ++k)
        logit += __shfl(v, k) * w2c[k];
    float mx = logit;
#pragma unroll
    for (int off = 32; off > 0; off >>= 1) mx = fmaxf(mx, __shfl_xor(mx, off));
    float ex = __expf(logit - mx);
    float s = ex;
#pragma unroll
    for (int off = 32; off > 0; off >>= 1) s += __shfl_xor(s, off);
    out[(size_t)node * NCLS + lane] = logit - mx - logf(s);
}

extern "C" void kernel_launch(void* const* d_in, const int* in_sizes, int n_in,
                              void* d_out, int out_size, void* d_ws, size_t ws_size,
                              hipStream_t stream) {
    const float* x  = (const float*)d_in[0];   // f32 [100000,512]
    const int*   ei = (const int*)d_in[1];     // int32 [2,3200000]
    const float* w1 = (const float*)d_in[2];   // f32 [512,16]
    const float* b1 = (const float*)d_in[3];   // f32 [16]
    const float* w2 = (const float*)d_in[4];   // f32 [16,64]
    const float* b2 = (const float*)d_in[5];   // f32 [64]
    const int* src = ei;
    const int* dst = ei + NEDGES;

    char* ws = (char*)d_ws;
    unsigned* gcnt = (unsigned*)(ws + 0);          //     2,048 B
    unsigned* offs = (unsigned*)(ws + 2048);       //   400,000 B
    unsigned* cnt  = (unsigned*)(ws + 402048);     //   400,000 B
    float*    dinv = (float*)   (ws + 802048);     //   400,000 B
    unsigned short* hs1 = (unsigned short*)(ws + 1202048);  // 3,200,000 B (bf16)
    unsigned short* hs2 = (unsigned short*)(ws + 4402048);  // 3,200,000 B (bf16)
    unsigned* part = (unsigned*)(ws + 7602048);    // 16,015,360 B (total ~23.6 MB)

    hipMemsetAsync(gcnt, 0, 2048, stream);
    k_fused1<<<NPB + NGB, 512, 0, stream>>>(src, dst, gcnt, part, x, w1, hs1);
    k_csr  <<<NB, 512, 0, stream>>>(gcnt, part, offs, cnt, dinv);
    k_agg1 <<<NNODES / 4, 256, 0, stream>>>(offs, cnt, part, hs1, dinv, b1, hs2);
    k_out2 <<<NNODES / 4, 256, 0, stream>>>(offs, cnt, part, hs2, dinv, w2, b2, (float*)d_out);
}

// Round 8
// 427.143 us; speedup vs baseline: 2.4834x; 1.1024x over previous
//
#include <hip/hip_runtime.h>

#define NNODES 100000
#define NEDGES 3200000
#define NFEAT  512
#define NHID   16
#define NCLS   64
#define NB     391      // buckets of 256 nodes (bucket = dst>>8)
#define CAP    10240    // per-bucket edge capacity (mean 8192, sd ~90 -> +22 sigma)
#define EPB    8192     // edges per partition block (391 partition blocks)
#define GTPB   8        // gemm tiles (16 rows) per gemm block
#define NGB    782      // ceil(6250 tiles / 8)

typedef short bf16x8 __attribute__((ext_vector_type(8)));
typedef float f32x4  __attribute__((ext_vector_type(4)));

__device__ __forceinline__ short f2bf(float f) {
    unsigned u = __float_as_uint(f);
    return (short)((u + 0x7FFFu + ((u >> 16) & 1u)) >> 16);
}
__device__ __forceinline__ float bf2f(unsigned short u) {
    return __uint_as_float((unsigned)u << 16);
}

struct PartShared {                 // 55,892 B (R3's proven k_part layout)
    unsigned hist[NB];
    unsigned scn[512];
    unsigned cursor[NB];
    unsigned delta[NB];
    unsigned staged[EPB];
    unsigned short pbkt[EPB];
};
struct GemmShared { short w1t[16][520]; };  // 16,640 B
union FusedShared { PartShared p; GemmShared g; };

// ---- kA: blocks [0,NB) partition edges (R3 k_part verbatim); blocks [NB,NB+NGB) x@W1.
// gemm output UNSCALED -> no dinv dependency -> true overlap with partition.
__global__ __launch_bounds__(512) void k_fused1(const int* __restrict__ src,
                                                const int* __restrict__ dst,
                                                unsigned* __restrict__ gcnt,
                                                unsigned* __restrict__ part,
                                                const float* __restrict__ x,
                                                const float* __restrict__ w1,
                                                unsigned short* __restrict__ hs1) {
    __shared__ FusedShared sh;
    int t = threadIdx.x;
    if (blockIdx.x < NB) {
        int base = blockIdx.x * EPB;
        int nblk = min(EPB, NEDGES - base);
        for (int i = t; i < NB; i += 512) sh.p.hist[i] = 0;
        __syncthreads();
        unsigned pk[16]; unsigned short bk[16];
#pragma unroll
        for (int j = 0; j < 16; ++j) {
            int o = t + j * 512;
            if (o < nblk) {
                int s = src[base + o], d = dst[base + o];
                pk[j] = (unsigned)s | ((unsigned)(d & 255) << 17);
                bk[j] = (unsigned short)(d >> 8);
                atomicAdd(&sh.p.hist[bk[j]], 1u);
            } else bk[j] = 0xFFFFu;
        }
        __syncthreads();
        sh.p.scn[t] = (t < NB) ? sh.p.hist[t] : 0u;
        __syncthreads();
#pragma unroll
        for (int off = 1; off < 512; off <<= 1) {
            unsigned a = (t >= off) ? sh.p.scn[t - off] : 0u;
            __syncthreads();
            sh.p.scn[t] += a;
            __syncthreads();
        }
        for (int i = t; i < NB; i += 512) {
            unsigned h = sh.p.hist[i];
            unsigned ex = sh.p.scn[i] - h;
            sh.p.cursor[i] = ex;
            unsigned gb = h ? atomicAdd(&gcnt[i], h) : 0u;
            sh.p.delta[i] = (unsigned)i * CAP + gb - ex;
        }
        __syncthreads();
#pragma unroll
        for (int j = 0; j < 16; ++j) {
            if (bk[j] != 0xFFFFu) {
                unsigned p = atomicAdd(&sh.p.cursor[bk[j]], 1u);
                sh.p.staged[p] = pk[j];
                sh.p.pbkt[p] = bk[j];
            }
        }
        __syncthreads();
        for (int i = t; i < nblk; i += 512) {
            unsigned b = sh.p.pbkt[i];
            unsigned d = sh.p.delta[b] + (unsigned)i;
            if (d < (b + 1u) * CAP) part[d] = sh.p.staged[i];   // overflow guard
        }
    } else {
        for (int idx = t; idx < NFEAT * NHID; idx += 512) {
            int k = idx >> 4, n = idx & 15;
            sh.g.w1t[n][k] = f2bf(w1[idx]);
        }
        __syncthreads();
        int wave = t >> 6, lane = t & 63;
        int tile = (int)(blockIdx.x - NB) * GTPB + wave;
        if (tile >= NNODES / 16) return;
        int m = lane & 15, q = lane >> 4;
        const float* xrow = x + (size_t)(tile * 16 + m) * NFEAT + q * 8;
        const short* wrow = &sh.g.w1t[m][q * 8];
        f32x4 acc = {0.f, 0.f, 0.f, 0.f};
#pragma unroll
        for (int kb = 0; kb < NFEAT / 32; ++kb) {
            float4 a0 = *(const float4*)(xrow + kb * 32);
            float4 a1 = *(const float4*)(xrow + kb * 32 + 4);
            bf16x8 a;
            a[0] = f2bf(a0.x); a[1] = f2bf(a0.y); a[2] = f2bf(a0.z); a[3] = f2bf(a0.w);
            a[4] = f2bf(a1.x); a[5] = f2bf(a1.y); a[6] = f2bf(a1.z); a[7] = f2bf(a1.w);
            bf16x8 bfr = *(const bf16x8*)(wrow + kb * 32);
            acc = __builtin_amdgcn_mfma_f32_16x16x32_bf16(a, bfr, acc, 0, 0, 0);
        }
        unsigned short* outp = hs1 + (size_t)(tile * 16) * NHID;
#pragma unroll
        for (int r = 0; r < 4; ++r)
            outp[(q * 4 + r) * NHID + m] = (unsigned short)f2bf(acc[r]);
    }
}

// ---- kB1: per-bucket degree hist (R4's proven k_dinv) -> dinv; scale own hs1 rows in place
__global__ __launch_bounds__(512) void k_scale(const unsigned* __restrict__ gcnt,
                                               const unsigned* __restrict__ part,
                                               float* __restrict__ dinv,
                                               unsigned short* __restrict__ hs1) {
    __shared__ unsigned hist[256];
    __shared__ float dl[256];
    int t = threadIdx.x, b = blockIdx.x;
    unsigned cb = min(gcnt[b], (unsigned)CAP);
    const unsigned* seg = part + (size_t)b * CAP;
    if (t < 256) hist[t] = 0;
    __syncthreads();
    for (unsigned i = t; i < cb; i += 512)
        atomicAdd(&hist[(seg[i] >> 17) & 255u], 1u);
    __syncthreads();
    if (t < 256) {
        dl[t] = rsqrtf((float)hist[t] + 1.f);               // +1 = self-loop
        int gn = b * 256 + t;
        if (gn < NNODES) dinv[gn] = dl[t];
    }
    __syncthreads();
    for (int i = t; i < 4096; i += 512) {                   // hs1[gn] *= dinv[gn]
        int nd = i >> 4, ff = i & 15;
        int gn = b * 256 + nd;
        if (gn < NNODES) {
            size_t ix = (size_t)gn * NHID + ff;
            hs1[ix] = (unsigned short)f2bf(bf2f(hs1[ix]) * dl[nd]);
        }
    }
}

// ---- kB2: fine sort in LDS (R3 k_csr logic) + layer-1 aggregate from LDS edge lists.
// Writes sorted list + offs/cnt for kC; hs2 pre-scaled by dinv.
__global__ __launch_bounds__(512) void k_sortagg1(const unsigned* __restrict__ gcnt,
                                                  unsigned* __restrict__ part,
                                                  unsigned* __restrict__ offs,
                                                  unsigned* __restrict__ cnt,
                                                  const unsigned short* __restrict__ hs1,
                                                  const float* __restrict__ b1,
                                                  unsigned short* __restrict__ hs2) {
    __shared__ unsigned staged[CAP];                        // 40 KB sorted src lists
    __shared__ unsigned hist[256], cum[256], cur[256];
    __shared__ float dl[256];
    int t = threadIdx.x, b = blockIdx.x;
    int lane = t & 63, wv = t >> 6;
    int f = lane & 15, slot = lane >> 4;
    unsigned cb = min(gcnt[b], (unsigned)CAP);
    unsigned* seg = part + (size_t)b * CAP;
    if (t < 256) hist[t] = 0;
    __syncthreads();
    for (unsigned i = t; i < cb; i += 512)
        atomicAdd(&hist[(seg[i] >> 17) & 255u], 1u);
    __syncthreads();
    if (t < 256) cum[t] = hist[t];
    __syncthreads();
#pragma unroll
    for (int off = 1; off < 256; off <<= 1) {
        unsigned a = (t >= off && t < 256) ? cum[t - off] : 0u;
        __syncthreads();
        if (t < 256) cum[t] += a;
        __syncthreads();
    }
    if (t < 256) {
        unsigned ex = cum[t] - hist[t];
        cur[t] = ex;
        dl[t] = rsqrtf((float)hist[t] + 1.f);
        int node = b * 256 + t;
        if (node < NNODES) {
            offs[node] = (unsigned)b * CAP + ex;
            cnt[node] = hist[t];
        }
    }
    __syncthreads();
    for (unsigned i = t; i < cb; i += 512) {
        unsigned p = seg[i];
        unsigned r = atomicAdd(&cur[(p >> 17) & 255u], 1u);
        staged[r] = p & 0x1FFFFu;                           // sorted src only
    }
    __syncthreads();
    for (unsigned i = t; i < cb; i += 512)
        seg[i] = staged[i];                                 // sorted list for kC (coalesced)
    // ---- layer-1 aggregate straight from LDS edge lists (hs1 pre-scaled by kB1) ----
    float b1f = b1[f];
    for (int nd = wv; nd < 256; nd += 8) {
        int gn = b * 256 + nd;
        if (gn >= NNODES) continue;
        int lstart = (int)(cum[nd] - hist[nd]);
        int deg = (int)hist[nd];
        float di = dl[nd];
        float acc = 0.f;
        int rounds = (deg + 31) >> 5, cl = deg - 1;
        for (int r = 0; r < rounds; ++r) {
            int jb = r * 32 + slot * 8;
            unsigned e[8];
#pragma unroll
            for (int u = 0; u < 8; ++u) e[u] = staged[lstart + min(jb + u, cl)];
            float a[8];
#pragma unroll
            for (int u = 0; u < 8; ++u) a[u] = bf2f(hs1[(size_t)e[u] * NHID + f]);
#pragma unroll
            for (int u = 0; u < 8; ++u) acc += (jb + u < deg) ? a[u] : 0.f;
        }
        acc += __shfl_xor(acc, 16);
        acc += __shfl_xor(acc, 32);
        float v = (acc + bf2f(hs1[(size_t)gn * NHID + f])) * di + b1f;
        v = v > 0.f ? v : 0.f;
        if (slot == 0) hs2[(size_t)gn * NHID + f] = (unsigned short)f2bf(v * di);
    }
}

// ---- kC: layer-2 aggregate + self + W2 matvec + b2 + log_softmax (R3 verbatim)
__global__ __launch_bounds__(256) void k_out2(const unsigned* __restrict__ offs,
                                              const unsigned* __restrict__ cnt,
                                              const unsigned* __restrict__ eb,
                                              const unsigned short* __restrict__ hs2,
                                              const float* __restrict__ dinv,
                                              const float* __restrict__ w2,
                                              const float* __restrict__ b2,
                                              float* __restrict__ out) {
    int tid = threadIdx.x;
    int node = blockIdx.x * 4 + (tid >> 6);
    int lane = tid & 63, f = lane & 15, slot = lane >> 4;
    unsigned start = offs[node];
    int deg = (int)cnt[node];
    float di = dinv[node];
    float w2c[NHID];
#pragma unroll
    for (int k = 0; k < NHID; ++k) w2c[k] = w2[k * NCLS + lane];
    float bb = b2[lane];
    float acc = 0.f;
    int rounds = (deg + 31) >> 5;
    int cl = deg - 1;
    for (int r = 0; r < rounds; ++r) {
        int jb = r * 32 + slot * 8;
        unsigned e[8];
#pragma unroll
        for (int u = 0; u < 8; ++u) e[u] = eb[start + min(jb + u, cl)];
        float a[8];
#pragma unroll
        for (int u = 0; u < 8; ++u) a[u] = bf2f(hs2[(size_t)e[u] * NHID + f]);
#pragma unroll
        for (int u = 0; u < 8; ++u) acc += (jb + u < deg) ? a[u] : 0.f;
    }
    acc += __shfl_xor(acc, 16);
    acc += __shfl_xor(acc, 32);
    float v = (acc + bf2f(hs2[(size_t)node * NHID + f])) * di;
    float logit = bb;
#pragma unroll
    for (int k = 0; k < NHID; ++k)
        logit += __shfl(v, k) * w2c[k];
    float mx = logit;
#pragma unroll
    for (int off = 32; off > 0; off >>= 1) mx = fmaxf(mx, __shfl_xor(mx, off));
    float ex = __expf(logit - mx);
    float s = ex;
#pragma unroll
    for (int off = 32; off > 0; off >>= 1) s += __shfl_xor(s, off);
    out[(size_t)node * NCLS + lane] = logit - mx - logf(s);
}

extern "C" void kernel_launch(void* const* d_in, const int* in_sizes, int n_in,
                              void* d_out, int out_size, void* d_ws, size_t ws_size,
                              hipStream_t stream) {
    const float* x  = (const float*)d_in[0];   // f32 [100000,512]
    const int*   ei = (const int*)d_in[1];     // int32 [2,3200000]
    const float* w1 = (const float*)d_in[2];   // f32 [512,16]
    const float* b1 = (const float*)d_in[3];   // f32 [16]
    const float* w2 = (const float*)d_in[4];   // f32 [16,64]
    const float* b2 = (const float*)d_in[5];   // f32 [64]
    const int* src = ei;
    const int* dst = ei + NEDGES;

    char* ws = (char*)d_ws;
    unsigned* gcnt = (unsigned*)(ws + 0);          //     2,048 B
    unsigned* offs = (unsigned*)(ws + 2048);       //   400,000 B
    unsigned* cnt  = (unsigned*)(ws + 402048);     //   400,000 B
    float*    dinv = (float*)   (ws + 802048);     //   400,000 B
    unsigned short* hs1 = (unsigned short*)(ws + 1202048);  // 3,200,000 B (bf16)
    unsigned short* hs2 = (unsigned short*)(ws + 4402048);  // 3,200,000 B (bf16)
    unsigned* part = (unsigned*)(ws + 7602048);    // 16,015,360 B (total ~23.6 MB)

    hipMemsetAsync(gcnt, 0, 2048, stream);
    k_fused1  <<<NB + NGB, 512, 0, stream>>>(src, dst, gcnt, part, x, w1, hs1);
    k_scale   <<<NB, 512, 0, stream>>>(gcnt, part, dinv, hs1);
    k_sortagg1<<<NB, 512, 0, stream>>>(gcnt, part, offs, cnt, hs1, b1, hs2);
    k_out2    <<<NNODES / 4, 256, 0, stream>>>(offs, cnt, part, hs2, dinv, w2, b2, (float*)d_out);
}